// Round 11
// baseline (374.135 us; speedup 1.0000x reference)
//
#include <hip/hip_runtime.h>
#include <cstddef>

#define NB 4
#define LSEQ 2048
#define BL (NB*LSEQ)
#define EMBD 256
#define DPROJ 1544
#define ZSTR 1600
#define DIN 512
#define DSTATE 256
#define CONVD 1024
#define NHD 8
#define PD 64
#define NC 32
#define NLAY 2
#define EPS 1e-5f

typedef __bf16 bf16x8 __attribute__((ext_vector_type(8)));
typedef float f32x4 __attribute__((ext_vector_type(4)));
typedef unsigned short u16;

// ---- static scratch ----
__device__ float g_h [(size_t)BL*EMBD];
__device__ u16   g_ub[(size_t)BL*EMBD];
__device__ float g_zx[(size_t)BL*ZSTR];
__device__ u16   g_xbcb[(size_t)BL*CONVD];     // bf16 conv output (xh|Bm|Cm)
__device__ float g_dt[(size_t)BL*NHD];
__device__ float g_acs[(size_t)NB*NHD*LSEQ];
__device__ float g_dAl[(size_t)NB*NHD*NC];
__device__ float g_y [(size_t)BL*DIN];
__device__ u16   g_yb[(size_t)BL*DIN];
__device__ u16   g_Sb[(size_t)NB*NC*NHD*PD*DSTATE];  // bf16 chunk states
__device__ float g_gt[(size_t)NB*NC*64*64];          // Gt[s][l] per (b,c), fp32
__device__ u16   g_wt1[(size_t)NLAY*ZSTR*EMBD];      // in_proj^T per layer
__device__ u16   g_wt2[(size_t)NLAY*EMBD*DIN];       // out_proj^T per layer
__device__ u16   g_wt3[(size_t)EMBD*EMBD];

__device__ inline u16 f2b(float f){
  unsigned u = __float_as_uint(f);
  return (u16)((u + 0x7fffu + ((u>>16)&1u)) >> 16);
}
__device__ inline float b2f(u16 v){
  return __uint_as_float(((unsigned)v) << 16);
}

typedef __attribute__((address_space(1))) const unsigned int gu32;
typedef __attribute__((address_space(3))) unsigned int lu32;
__device__ __forceinline__ void gl_lds16(const u16* g, u16* l){
  __builtin_amdgcn_global_load_lds((gu32*)g, (lu32*)l, 16, 0, 0);
}

// ---- embedding gather + RMSNorm(norm_w[0]) fused ----
__global__ void k_embedrms(const float* __restrict__ x, const float* __restrict__ emb,
                           const float* __restrict__ w) {
  int row = blockIdx.x, t = threadIdx.x;
  int idx = (int)(255.0f * x[row]);
  idx = idx < 0 ? 0 : (idx > 255 ? 255 : idx);
  float v = emb[idx*EMBD + t];
  g_h[(size_t)row*EMBD + t] = v;
  float ss = v*v;
  #pragma unroll
  for (int o=32;o>0;o>>=1) ss += __shfl_down(ss,o,64);
  __shared__ float ls[4];
  if ((t&63)==0) ls[t>>6]=ss;
  __syncthreads();
  float tot = ls[0]+ls[1]+ls[2]+ls[3];
  float r = rsqrtf(tot*(1.0f/EMBD) + EPS);
  g_ub[(size_t)row*EMBD + t] = f2b(v*r*w[t]);
}

// ---- RMSNorm over 256, bf16 out ----
__global__ void k_rmsnorm(const float* __restrict__ in, const float* __restrict__ w,
                          u16* __restrict__ out) {
  int row = blockIdx.x, t = threadIdx.x;
  float v = in[(size_t)row*EMBD + t];
  float ss = v*v;
  #pragma unroll
  for (int o=32;o>0;o>>=1) ss += __shfl_down(ss,o,64);
  __shared__ float ls[4];
  if ((t&63)==0) ls[t>>6]=ss;
  __syncthreads();
  float tot = ls[0]+ls[1]+ls[2]+ls[3];
  float r = rsqrtf(tot*(1.0f/EMBD) + EPS);
  out[(size_t)row*EMBD + t] = f2b(v*r*w[t]);
}

// ---- all weight transposes in one launch (280 blocks) ----
__global__ void k_wtall(const float* __restrict__ inpw, const float* __restrict__ outw,
                        const float* __restrict__ headw) {
  __shared__ float tb[64][65];
  int id = blockIdx.x, tid = threadIdx.x;
  const float* W; u16* WT; int K, N, n0, k0;
  if (id < 200) {
    int l = id/100, r = id%100;
    K = EMBD; N = DPROJ; n0 = (r%25)*64; k0 = (r/25)*64;
    W = inpw + (size_t)l*EMBD*DPROJ; WT = g_wt1 + (size_t)l*ZSTR*EMBD;
  } else if (id < 264) {
    int r = id-200; int l = r/32; r %= 32;
    K = DIN; N = EMBD; n0 = (r%4)*64; k0 = (r/4)*64;
    W = outw + (size_t)l*DIN*EMBD; WT = g_wt2 + (size_t)l*EMBD*DIN;
  } else {
    int r = id-264;
    K = EMBD; N = EMBD; n0 = (r%4)*64; k0 = (r/4)*64;
    W = headw; WT = g_wt3;
  }
  #pragma unroll
  for (int e=0;e<16;e++){
    int idx = tid + e*256;
    int kk = idx>>6, nn = idx&63;
    tb[kk][nn] = (n0+nn < N) ? W[(size_t)(k0+kk)*N + n0+nn] : 0.f;
  }
  __syncthreads();
  #pragma unroll
  for (int e=0;e<16;e++){
    int idx = tid + e*256;
    int nn = idx>>6, kk = idx&63;
    WT[(size_t)(n0+nn)*K + k0+kk] = f2b(tb[kk][nn]);
  }
}

// ---- bf16 MFMA GEMM, global_load_lds staging with pre-swizzled source ----
template<int K, bool RES>
__global__ __launch_bounds__(256) void k_mfma_gemm(
    const u16* __restrict__ A, const u16* __restrict__ WT,
    const float* __restrict__ addC, float* __restrict__ C, int nstride)
{
  __shared__ u16 sA[128*64];
  __shared__ u16 sB[64*64];
  const int tid = threadIdx.x;
  const int lane = tid & 63;
  const int w = tid >> 6;
  const int bm = blockIdx.y * 128;
  const int bn = blockIdx.x * 64;
  const int r15 = lane & 15, kg = lane >> 4;
  const int lr = lane >> 3, cs = lane & 7;
  // linear LDS dest + inverse-swizzled global source (rule: both-sides-or-neither)
  const u16* aSrc[4]; u16* aDst[4];
  const u16* bSrc[2]; u16* bDst[2];
  #pragma unroll
  for (int it = 0; it < 4; ++it) {
    int row = it*32 + w*8 + lr;
    int ck = cs ^ (row & 7);
    aSrc[it] = A + (size_t)(bm+row)*K + ck*8;
    aDst[it] = sA + it*2048 + w*512;
  }
  #pragma unroll
  for (int it = 0; it < 2; ++it) {
    int row = it*32 + w*8 + lr;
    int ck = cs ^ (row & 7);
    bSrc[it] = WT + (size_t)(bn+row)*K + ck*8;
    bDst[it] = sB + it*2048 + w*512;
  }
  f32x4 acc[2][4] = {};
  for (int k0 = 0; k0 < K; k0 += 64) {
    #pragma unroll
    for (int it = 0; it < 4; ++it) gl_lds16(aSrc[it] + k0, aDst[it]);
    #pragma unroll
    for (int it = 0; it < 2; ++it) gl_lds16(bSrc[it] + k0, bDst[it]);
    __syncthreads();
    #pragma unroll
    for (int ks = 0; ks < 2; ++ks) {
      bf16x8 af[2], bfr[4];
      #pragma unroll
      for (int mr = 0; mr < 2; ++mr) {
        int row = w*32 + mr*16 + r15;
        int c16 = ks*4 + kg;
        af[mr] = *(const bf16x8*)(sA + row*64 + ((c16 ^ (row&7))*8));
      }
      #pragma unroll
      for (int nr = 0; nr < 4; ++nr) {
        int row = nr*16 + r15;
        int c16 = ks*4 + kg;
        bfr[nr] = *(const bf16x8*)(sB + row*64 + ((c16 ^ (row&7))*8));
      }
      #pragma unroll
      for (int mr = 0; mr < 2; ++mr)
        #pragma unroll
        for (int nr = 0; nr < 4; ++nr)
          acc[mr][nr] = __builtin_amdgcn_mfma_f32_16x16x32_bf16(af[mr], bfr[nr], acc[mr][nr], 0, 0, 0);
    }
    __syncthreads();
  }
  #pragma unroll
  for (int mr = 0; mr < 2; ++mr)
    #pragma unroll
    for (int j = 0; j < 4; ++j) {
      int grow = bm + w*32 + mr*16 + (lane>>4)*4 + j;
      #pragma unroll
      for (int nr = 0; nr < 4; ++nr) {
        int gcol = bn + nr*16 + (lane & 15);
        float v = acc[mr][nr][j];
        if (RES) v += addC[(size_t)grow*nstride + gcol];
        C[(size_t)grow*nstride + gcol] = v;
      }
    }
}

// ---- fused dt + per-chunk scan ----
__global__ void k_dtscan(const float* __restrict__ dtb, const float* __restrict__ alog) {
  int gid = blockIdx.x;
  int cix = gid & (NC-1), bh = gid >> 5;
  int b = bh >> 3, h = bh & 7;
  int t = threadIdx.x;
  int row = b*LSEQ + cix*64 + t;
  float v = g_zx[(size_t)row*ZSTR + 1536 + h] + dtb[h];
  float sp = (v > 20.f) ? v : log1pf(__expf(v));
  g_dt[(size_t)row*NHD + h] = sp;
  float a = -__expf(alog[h]) * sp;
  #pragma unroll
  for (int o=1;o<64;o<<=1){
    float p = __shfl_up(a,o,64);
    if (t>=o) a += p;
  }
  g_acs[(size_t)bh*LSEQ + cix*64 + t] = a;
  if (t==63) g_dAl[(size_t)bh*NC + cix] = a;
}

// ---- depthwise causal conv (k=4) + bias + SiLU, bf16 out ----
__global__ __launch_bounds__(256) void k_conv(const float* __restrict__ cw,
                                              const float* __restrict__ cb) {
  int r0 = blockIdx.x * 4;
  int t0 = r0 & (LSEQ-1);
  int c  = threadIdx.x * 4;
  f32x4 v[7];
  #pragma unroll
  for (int i = 0; i < 7; ++i) {
    int tr = t0 - 3 + i;
    if (tr >= 0)
      v[i] = *(const f32x4*)(&g_zx[(size_t)(r0-3+i)*ZSTR + DIN + c]);
    else
      v[i] = (f32x4){0.f,0.f,0.f,0.f};
  }
  f32x4 w0 = *(const f32x4*)(&cw[(c+0)*4]);
  f32x4 w1 = *(const f32x4*)(&cw[(c+1)*4]);
  f32x4 w2 = *(const f32x4*)(&cw[(c+2)*4]);
  f32x4 w3 = *(const f32x4*)(&cw[(c+3)*4]);
  f32x4 bi = *(const f32x4*)(&cb[c]);
  #pragma unroll
  for (int j = 0; j < 4; ++j) {
    float o[4];
    #pragma unroll
    for (int ch = 0; ch < 4; ++ch) {
      const f32x4& wv = (ch==0)?w0:(ch==1)?w1:(ch==2)?w2:w3;
      float acc = bi[ch];
      #pragma unroll
      for (int k = 0; k < 4; ++k) acc += wv[k] * v[j+k][ch];
      o[ch] = acc / (1.f + __expf(-acc));
    }
    u16 o16[4];
    #pragma unroll
    for (int ch = 0; ch < 4; ++ch) o16[ch] = f2b(o[ch]);
    *(uint2*)(&g_xbcb[(size_t)(r0+j)*CONVD + c]) = *(const uint2*)o16;
  }
}

// ---- Gt = Bm·Cm^T once per (b,c) ----
__global__ __launch_bounds__(256) void k_gmat() {
  int bc = blockIdx.x;
  int b = bc >> 5, cix = bc & 31;
  int row0 = b*LSEQ + cix*64;
  int tid = threadIdx.x, lane = tid & 63, w = tid >> 6;
  int r15 = lane & 15, kq = lane >> 4;
  __shared__ u16 sBm[64*256];
  __shared__ u16 sCm[64*256];
  #pragma unroll
  for (int e = 0; e < 8; ++e) {
    int idx = tid + e*256;
    int row = idx >> 5, c16 = idx & 31;
    uint4 vb = *(const uint4*)(&g_xbcb[(size_t)(row0+row)*CONVD + 512 + c16*8]);
    uint4 vc = *(const uint4*)(&g_xbcb[(size_t)(row0+row)*CONVD + 768 + c16*8]);
    int sw = (c16 ^ (row&7))*8;
    *(uint4*)(&sBm[row*256 + sw]) = vb;
    *(uint4*)(&sCm[row*256 + sw]) = vc;
  }
  __syncthreads();
  int S0 = w*16;
  f32x4 acc[4] = {};
  #pragma unroll
  for (int ks = 0; ks < 8; ++ks) {
    int ch = ks*4 + kq;
    int rA = S0 + r15;
    bf16x8 af = *(const bf16x8*)(&sBm[rA*256 + ((ch ^ (rA&7))*8)]);
    #pragma unroll
    for (int lt = 0; lt < 4; ++lt) {
      int rB = lt*16 + r15;
      bf16x8 bf = *(const bf16x8*)(&sCm[rB*256 + ((ch ^ (rB&7))*8)]);
      acc[lt] = __builtin_amdgcn_mfma_f32_16x16x32_bf16(af, bf, acc[lt], 0, 0, 0);
    }
  }
  float* Gt = &g_gt[(size_t)bc*64*64];
  #pragma unroll
  for (int lt = 0; lt < 4; ++lt)
    #pragma unroll
    for (int j = 0; j < 4; ++j)
      Gt[(S0 + kq*4 + j)*64 + lt*16 + r15] = acc[lt][j];
}

// ---- fused SSD part 1 per (b,c,h) ----
__global__ __launch_bounds__(512) void k_ssd1(const float* __restrict__ Dp) {
  int g = blockIdx.x;
  int h = g & 7, bc = g >> 3;
  int b = bc >> 5, cix = bc & 31;
  int row0 = b*LSEQ + cix*64;
  int bh = b*NHD + h;
  int tid = threadIdx.x;
  int lane = tid & 63, w = tid >> 6;
  int r15 = lane & 15, kq = lane >> 4;

  __shared__ u16 sBmt[256*64];
  __shared__ u16 sXt [64*64];
  __shared__ u16 sXdt[64*64];
  __shared__ u16 sM  [64*64];
  __shared__ float sAc[64];

  {
    int l = tid & 63;
    #pragma unroll
    for (int it = 0; it < 4; ++it) {
      int nc = (tid >> 6) + it*8;
      uint4 v4 = *(const uint4*)(&g_xbcb[(size_t)(row0+l)*CONVD + 512 + nc*8]);
      const u16* hp = (const u16*)&v4;
      #pragma unroll
      for (int i = 0; i < 8; ++i) {
        int n = nc*8 + i;
        sBmt[n*64 + (((l>>3) ^ (n&7))<<3) + (l&7)] = hp[i];
      }
    }
  }
  {
    int s = tid & 63, pc = tid >> 6;
    float ac  = g_acs[(size_t)bh*LSEQ + cix*64 + s];
    float dal = g_dAl[(size_t)bh*NC + cix];
    float dtv = g_dt[(size_t)(row0+s)*NHD + h];
    float dec = __expf(dal - ac);
    if (pc == 0) sAc[s] = ac;
    uint4 v4 = *(const uint4*)(&g_xbcb[(size_t)(row0+s)*CONVD + h*64 + pc*8]);
    const u16* hp = (const u16*)&v4;
    #pragma unroll
    for (int i = 0; i < 8; ++i) {
      int p = pc*8 + i;
      float xv = b2f(hp[i]) * dtv;
      int sw = (((s>>3) ^ (p&7))<<3) + (s&7);
      sXt [p*64 + sw] = f2b(xv);
      sXdt[p*64 + sw] = f2b(xv*dec);
    }
  }
  __syncthreads();

  {
    int S0  = (w >> 1)*16;
    int L0a = ((2*w) & 3)*16, L0b = L0a + 16;
    const float* Gt = &g_gt[(size_t)bc*64*64];
    int l0 = L0a + r15, l1 = L0b + r15;
    float acl0 = sAc[l0], acl1 = sAc[l1];
    #pragma unroll
    for (int j = 0; j < 4; ++j) {
      int s_ = S0 + kq*4 + j;
      float acs_ = sAc[s_];
      float g0 = Gt[s_*64 + l0];
      float g1 = Gt[s_*64 + l1];
      float m0 = (s_ <= l0) ? g0*__expf(acl0 - acs_) : 0.f;
      float m1 = (s_ <= l1) ? g1*__expf(acl1 - acs_) : 0.f;
      sM[l0*64 + (((s_>>3) ^ (l0&7))<<3) + (s_&7)] = f2b(m0);
      sM[l1*64 + (((s_>>3) ^ (l1&7))<<3) + (s_&7)] = f2b(m1);
    }
  }
  __syncthreads();

  {
    int lt = w >> 1;
    int pt0 = (2*w) & 3;
    int L0 = lt*16, P0 = pt0*16;
    f32x4 acc0 = {}, acc1 = {};
    #pragma unroll
    for (int ks = 0; ks < 2; ++ks) {
      int ch = ks*4 + kq;
      int sw = (ch ^ (r15&7))<<3;
      bf16x8 af = *(const bf16x8*)(&sM [(L0+r15)*64 + sw]);
      bf16x8 b0 = *(const bf16x8*)(&sXt[(P0+r15)*64 + sw]);
      bf16x8 b1 = *(const bf16x8*)(&sXt[(P0+16+r15)*64 + sw]);
      acc0 = __builtin_amdgcn_mfma_f32_16x16x32_bf16(af, b0, acc0, 0, 0, 0);
      acc1 = __builtin_amdgcn_mfma_f32_16x16x32_bf16(af, b1, acc1, 0, 0, 0);
    }
    float Dv = Dp[h];
    #pragma unroll
    for (int j = 0; j < 4; ++j) {
      int l = L0 + kq*4 + j;
      int p0 = P0 + r15, p1 = p0 + 16;
      float xh0 = b2f(g_xbcb[(size_t)(row0+l)*CONVD + h*64 + p0]);
      float xh1 = b2f(g_xbcb[(size_t)(row0+l)*CONVD + h*64 + p1]);
      g_y[(size_t)(row0+l)*DIN + h*64 + p0] = acc0[j] + Dv*xh0;
      g_y[(size_t)(row0+l)*DIN + h*64 + p1] = acc1[j] + Dv*xh1;
    }
  }

  {
    int P0 = (w >> 1)*16;
    int N0 = (w & 1)*128;
    f32x4 acc[8] = {};
    #pragma unroll
    for (int ks = 0; ks < 2; ++ks) {
      int ch = ks*4 + kq;
      int sw = (ch ^ (r15&7))<<3;
      bf16x8 af = *(const bf16x8*)(&sXdt[(P0+r15)*64 + sw]);
      #pragma unroll
      for (int nt = 0; nt < 8; ++nt) {
        bf16x8 bf = *(const bf16x8*)(&sBmt[(N0+nt*16+r15)*64 + sw]);
        acc[nt] = __builtin_amdgcn_mfma_f32_16x16x32_bf16(af, bf, acc[nt], 0, 0, 0);
      }
    }
    size_t Sbase = ((size_t)(bc*NHD + h))*PD*DSTATE;
    #pragma unroll
    for (int nt = 0; nt < 8; ++nt)
      #pragma unroll
      for (int j = 0; j < 4; ++j) {
        int p = P0 + kq*4 + j;
        int n = N0 + nt*16 + r15;
        g_Sb[Sbase + (size_t)p*DSTATE + n] = f2b(acc[nt][j]);
      }
  }
}

// ---- exclusive inter-chunk scan (bf16 storage, fp32 carry) ----
__global__ void k_sscan() {
  int i = blockIdx.x*256 + threadIdx.x;
  int pn = i & (PD*DSTATE-1);
  int bh = i >> 14;
  int b = bh >> 3, h = bh & 7;
  float carry = 0.f;
  for (int c=0;c<NC;c++){
    size_t off = ((size_t)((b*NC+c)*NHD + h))*PD*DSTATE + pn;
    float cur = b2f(g_Sb[off]);
    g_Sb[off] = f2b(carry);
    carry = carry*__expf(g_dAl[(size_t)(b*NHD+h)*NC + c]) + cur;
  }
}

// ---- fused SSD part 2 per (b,c,h) ----
__global__ __launch_bounds__(256) void k_ssd2() {
  int g = blockIdx.x;
  int h = g & 7, bc = g >> 3;
  int b = bc >> 5, cix = bc & 31;
  int row0 = b*LSEQ + cix*64;
  int bh = b*NHD + h;
  int tid = threadIdx.x;
  int lane = tid & 63, w = tid >> 6;
  int r15 = lane & 15, kq = lane >> 4;
  __shared__ u16 sSb[64*256];
  __shared__ float sAc[64];
  size_t Sbase = ((size_t)(bc*NHD + h))*PD*DSTATE;
  #pragma unroll
  for (int it = 0; it < 8; ++it) {
    int e = tid + it*256;
    int c16 = e & 31, p = e >> 5;
    uint4 v4 = *(const uint4*)(&g_Sb[Sbase + (size_t)p*DSTATE + c16*8]);
    *(uint4*)(&sSb[p*256 + ((c16 ^ (p&7))<<3)]) = v4;
  }
  if (tid < 64) sAc[tid] = g_acs[(size_t)bh*LSEQ + cix*64 + tid];
  __syncthreads();
  int L0 = w*16;
  const u16* Ab = &g_xbcb[(size_t)(row0+L0+r15)*CONVD + 768];
  f32x4 acc[4] = {};
  #pragma unroll
  for (int ks = 0; ks < 8; ++ks) {
    int ch = ks*4 + kq;
    bf16x8 af = *(const bf16x8*)(Ab + ch*8);
    #pragma unroll
    for (int pt = 0; pt < 4; ++pt) {
      bf16x8 bf = *(const bf16x8*)(&sSb[(pt*16+r15)*256 + ((ch ^ (r15&7))<<3)]);
      acc[pt] = __builtin_amdgcn_mfma_f32_16x16x32_bf16(af, bf, acc[pt], 0, 0, 0);
    }
  }
  #pragma unroll
  for (int j = 0; j < 4; ++j) {
    int l = L0 + kq*4 + j;
    float ev = __expf(sAc[l]);
    #pragma unroll
    for (int pt = 0; pt < 4; ++pt) {
      int p = pt*16 + r15;
      g_y[(size_t)(row0+l)*DIN + h*64 + p] += ev*acc[pt][j];
    }
  }
}

// ---- gated RMSNorm over 512, vectorized: 2 rows/block, f32x4/thread ----
__global__ void k_gated(const float* __restrict__ gw) {
  int rl = threadIdx.x >> 7;
  int row = blockIdx.x*2 + rl;
  int t = threadIdx.x & 127;
  f32x4 y4 = *(const f32x4*)(&g_y[(size_t)row*DIN + t*4]);
  f32x4 z4 = *(const f32x4*)(&g_zx[(size_t)row*ZSTR + t*4]);
  float v[4]; float ss = 0.f;
  #pragma unroll
  for (int j = 0; j < 4; ++j) {
    float z = z4[j];
    float val = y4[j] * (z/(1.f+__expf(-z)));
    v[j] = val; ss += val*val;
  }
  #pragma unroll
  for (int o=32;o>0;o>>=1) ss += __shfl_down(ss,o,64);
  __shared__ float ls[4];
  if ((threadIdx.x&63)==0) ls[threadIdx.x>>6]=ss;
  __syncthreads();
  float tot = ls[rl*2] + ls[rl*2+1];
  float r = rsqrtf(tot*(1.f/DIN) + EPS);
  u16 o16[4];
  #pragma unroll
  for (int j = 0; j < 4; ++j) o16[j] = f2b(v[j]*r*gw[t*4+j]);
  *(uint2*)(&g_yb[(size_t)row*DIN + t*4]) = *(const uint2*)o16;
}

extern "C" void kernel_launch(void* const* d_in, const int* in_sizes, int n_in,
                              void* d_out, int out_size, void* d_ws, size_t ws_size,
                              hipStream_t stream) {
  const float* x     = (const float*)d_in[0];
  const float* emb   = (const float*)d_in[1];
  const float* inpw  = (const float*)d_in[2];
  const float* convw = (const float*)d_in[3];
  const float* convb = (const float*)d_in[4];
  const float* dtb   = (const float*)d_in[5];
  const float* alog  = (const float*)d_in[6];
  const float* Dp    = (const float*)d_in[7];
  const float* gnw   = (const float*)d_in[8];
  const float* outw  = (const float*)d_in[9];
  const float* normw = (const float*)d_in[10];
  const float* normf = (const float*)d_in[11];
  const float* headw = (const float*)d_in[12];
  float* out = (float*)d_out;
  (void)in_sizes; (void)n_in; (void)out_size; (void)d_ws; (void)ws_size;

  float *ph, *pzx;
  u16 *pub, *pyb, *pwt1, *pwt2, *pwt3;
  hipGetSymbolAddress((void**)&ph,   HIP_SYMBOL(g_h));
  hipGetSymbolAddress((void**)&pub,  HIP_SYMBOL(g_ub));
  hipGetSymbolAddress((void**)&pzx,  HIP_SYMBOL(g_zx));
  hipGetSymbolAddress((void**)&pyb,  HIP_SYMBOL(g_yb));
  hipGetSymbolAddress((void**)&pwt1, HIP_SYMBOL(g_wt1));
  hipGetSymbolAddress((void**)&pwt2, HIP_SYMBOL(g_wt2));
  hipGetSymbolAddress((void**)&pwt3, HIP_SYMBOL(g_wt3));

  k_embedrms<<<BL, 256, 0, stream>>>(x, emb, normw);
  k_wtall<<<280, 256, 0, stream>>>(inpw, outw, headw);
  for (int i=0;i<NLAY;i++){
    k_mfma_gemm<EMBD,false><<<dim3(ZSTR/64, BL/128), 256, 0, stream>>>(
        pub, pwt1 + (size_t)i*ZSTR*EMBD, nullptr, pzx, ZSTR);
    k_dtscan<<<NB*NHD*NC, 64, 0, stream>>>(dtb + i*NHD, alog + i*NHD);
    k_conv<<<BL/4, 256, 0, stream>>>(convw + i*CONVD*4, convb + i*CONVD);
    k_gmat<<<NB*NC, 256, 0, stream>>>();
    k_ssd1<<<NB*NC*NHD, 512, 0, stream>>>(Dp + i*NHD);
    k_sscan<<<(NB*NHD*PD*DSTATE)/256, 256, 0, stream>>>();
    k_ssd2<<<NB*NC*NHD, 256, 0, stream>>>();
    k_gated<<<BL/2, 256, 0, stream>>>(gnw + i*DIN);
    k_mfma_gemm<DIN,true><<<dim3(EMBD/64, BL/128), 256, 0, stream>>>(
        pyb, pwt2 + (size_t)i*EMBD*DIN, ph, ph, EMBD);
    k_rmsnorm<<<BL, 256, 0, stream>>>(ph, (i==NLAY-1) ? normf : normw + (i+1)*EMBD, pub);
  }
  k_mfma_gemm<EMBD,false><<<dim3(EMBD/64, BL/128), 256, 0, stream>>>(pub, pwt3, nullptr, out, EMBD);
}

// Round 13
// 324.290 us; speedup vs baseline: 1.1537x; 1.1537x over previous
//
#include <hip/hip_runtime.h>
#include <cstddef>

#define NB 4
#define LSEQ 2048
#define BL (NB*LSEQ)
#define EMBD 256
#define DPROJ 1544
#define ZSTR 1600
#define DIN 512
#define DSTATE 256
#define CONVD 1024
#define NHD 8
#define PD 64
#define NC 32
#define NLAY 2
#define EPS 1e-5f

typedef __bf16 bf16x8 __attribute__((ext_vector_type(8)));
typedef float f32x4 __attribute__((ext_vector_type(4)));
typedef unsigned short u16;

// ---- static scratch ----
__device__ float g_h [(size_t)BL*EMBD];
__device__ u16   g_ub[(size_t)BL*EMBD];
__device__ float g_zx[(size_t)BL*ZSTR];
__device__ u16   g_xbcb[(size_t)BL*CONVD];     // bf16 conv output (xh|Bm|Cm)
__device__ float g_dt[(size_t)BL*NHD];
__device__ float g_acs[(size_t)NB*NHD*LSEQ];
__device__ float g_dAl[(size_t)NB*NHD*NC];
__device__ float g_y [(size_t)BL*DIN];
__device__ u16   g_yb[(size_t)BL*DIN];
__device__ u16   g_Sb[(size_t)NB*NC*NHD*PD*DSTATE];  // bf16 chunk states
__device__ float g_gt[(size_t)NB*NC*64*64];          // Gt[s][l] per (b,c), fp32
__device__ u16   g_wt1[(size_t)NLAY*ZSTR*EMBD];      // in_proj^T per layer
__device__ u16   g_wt2[(size_t)NLAY*EMBD*DIN];       // out_proj^T per layer
__device__ u16   g_wt3[(size_t)EMBD*EMBD];

__device__ inline u16 f2b(float f){
  unsigned u = __float_as_uint(f);
  return (u16)((u + 0x7fffu + ((u>>16)&1u)) >> 16);
}
__device__ inline float b2f(u16 v){
  return __uint_as_float(((unsigned)v) << 16);
}

// ---- embedding gather + RMSNorm(norm_w[0]) fused ----
__global__ void k_embedrms(const float* __restrict__ x, const float* __restrict__ emb,
                           const float* __restrict__ w) {
  int row = blockIdx.x, t = threadIdx.x;
  int idx = (int)(255.0f * x[row]);
  idx = idx < 0 ? 0 : (idx > 255 ? 255 : idx);
  float v = emb[idx*EMBD + t];
  g_h[(size_t)row*EMBD + t] = v;
  float ss = v*v;
  #pragma unroll
  for (int o=32;o>0;o>>=1) ss += __shfl_down(ss,o,64);
  __shared__ float ls[4];
  if ((t&63)==0) ls[t>>6]=ss;
  __syncthreads();
  float tot = ls[0]+ls[1]+ls[2]+ls[3];
  float r = rsqrtf(tot*(1.0f/EMBD) + EPS);
  g_ub[(size_t)row*EMBD + t] = f2b(v*r*w[t]);
}

// ---- RMSNorm over 256, bf16 out ----
__global__ void k_rmsnorm(const float* __restrict__ in, const float* __restrict__ w,
                          u16* __restrict__ out) {
  int row = blockIdx.x, t = threadIdx.x;
  float v = in[(size_t)row*EMBD + t];
  float ss = v*v;
  #pragma unroll
  for (int o=32;o>0;o>>=1) ss += __shfl_down(ss,o,64);
  __shared__ float ls[4];
  if ((t&63)==0) ls[t>>6]=ss;
  __syncthreads();
  float tot = ls[0]+ls[1]+ls[2]+ls[3];
  float r = rsqrtf(tot*(1.0f/EMBD) + EPS);
  out[(size_t)row*EMBD + t] = f2b(v*r*w[t]);
}

// ---- all weight transposes in one launch (280 blocks) ----
__global__ void k_wtall(const float* __restrict__ inpw, const float* __restrict__ outw,
                        const float* __restrict__ headw) {
  __shared__ float tb[64][65];
  int id = blockIdx.x, tid = threadIdx.x;
  const float* W; u16* WT; int K, N, n0, k0;
  if (id < 200) {
    int l = id/100, r = id%100;
    K = EMBD; N = DPROJ; n0 = (r%25)*64; k0 = (r/25)*64;
    W = inpw + (size_t)l*EMBD*DPROJ; WT = g_wt1 + (size_t)l*ZSTR*EMBD;
  } else if (id < 264) {
    int r = id-200; int l = r/32; r %= 32;
    K = DIN; N = EMBD; n0 = (r%4)*64; k0 = (r/4)*64;
    W = outw + (size_t)l*DIN*EMBD; WT = g_wt2 + (size_t)l*EMBD*DIN;
  } else {
    int r = id-264;
    K = EMBD; N = EMBD; n0 = (r%4)*64; k0 = (r/4)*64;
    W = headw; WT = g_wt3;
  }
  #pragma unroll
  for (int e=0;e<16;e++){
    int idx = tid + e*256;
    int kk = idx>>6, nn = idx&63;
    tb[kk][nn] = (n0+nn < N) ? W[(size_t)(k0+kk)*N + n0+nn] : 0.f;
  }
  __syncthreads();
  #pragma unroll
  for (int e=0;e<16;e++){
    int idx = tid + e*256;
    int nn = idx>>6, kk = idx&63;
    WT[(size_t)(n0+nn)*K + k0+kk] = f2b(tb[kk][nn]);
  }
}

// ---- bf16 MFMA GEMM (reg-staged, round-10 verbatim) ----
template<int K, bool RES>
__global__ __launch_bounds__(256) void k_mfma_gemm(
    const u16* __restrict__ A, const u16* __restrict__ WT,
    const float* __restrict__ addC, float* __restrict__ C, int nstride)
{
  __shared__ u16 sA[128*64];
  __shared__ u16 sB[64*64];
  const int tid = threadIdx.x;
  const int lane = tid & 63;
  const int w = tid >> 6;
  const int bm = blockIdx.y * 128;
  const int bn = blockIdx.x * 64;
  const int r15 = lane & 15, kg = lane >> 4;
  f32x4 acc[2][4] = {};
  for (int k0 = 0; k0 < K; k0 += 64) {
    #pragma unroll
    for (int it = 0; it < 4; ++it) {
      int ch = it*256 + tid;
      int row = ch >> 3, c16 = ch & 7;
      uint4 v = *(const uint4*)(A + (size_t)(bm+row)*K + k0 + c16*8);
      *(uint4*)(sA + row*64 + ((c16 ^ (row&7))*8)) = v;
    }
    #pragma unroll
    for (int it = 0; it < 2; ++it) {
      int ch = it*256 + tid;
      int row = ch >> 3, c16 = ch & 7;
      uint4 v = *(const uint4*)(WT + (size_t)(bn+row)*K + k0 + c16*8);
      *(uint4*)(sB + row*64 + ((c16 ^ (row&7))*8)) = v;
    }
    __syncthreads();
    #pragma unroll
    for (int ks = 0; ks < 2; ++ks) {
      bf16x8 af[2], bfr[4];
      #pragma unroll
      for (int mr = 0; mr < 2; ++mr) {
        int row = w*32 + mr*16 + r15;
        int c16 = ks*4 + kg;
        af[mr] = *(const bf16x8*)(sA + row*64 + ((c16 ^ (row&7))*8));
      }
      #pragma unroll
      for (int nr = 0; nr < 4; ++nr) {
        int row = nr*16 + r15;
        int c16 = ks*4 + kg;
        bfr[nr] = *(const bf16x8*)(sB + row*64 + ((c16 ^ (row&7))*8));
      }
      #pragma unroll
      for (int mr = 0; mr < 2; ++mr)
        #pragma unroll
        for (int nr = 0; nr < 4; ++nr)
          acc[mr][nr] = __builtin_amdgcn_mfma_f32_16x16x32_bf16(af[mr], bfr[nr], acc[mr][nr], 0, 0, 0);
    }
    __syncthreads();
  }
  #pragma unroll
  for (int mr = 0; mr < 2; ++mr)
    #pragma unroll
    for (int j = 0; j < 4; ++j) {
      int grow = bm + w*32 + mr*16 + (lane>>4)*4 + j;
      #pragma unroll
      for (int nr = 0; nr < 4; ++nr) {
        int gcol = bn + nr*16 + (lane & 15);
        float v = acc[mr][nr][j];
        if (RES) v += addC[(size_t)grow*nstride + gcol];
        C[(size_t)grow*nstride + gcol] = v;
      }
    }
}

// ---- fused dt + per-chunk scan ----
__global__ void k_dtscan(const float* __restrict__ dtb, const float* __restrict__ alog) {
  int gid = blockIdx.x;
  int cix = gid & (NC-1), bh = gid >> 5;
  int b = bh >> 3, h = bh & 7;
  int t = threadIdx.x;
  int row = b*LSEQ + cix*64 + t;
  float v = g_zx[(size_t)row*ZSTR + 1536 + h] + dtb[h];
  float sp = (v > 20.f) ? v : log1pf(__expf(v));
  g_dt[(size_t)row*NHD + h] = sp;
  float a = -__expf(alog[h]) * sp;
  #pragma unroll
  for (int o=1;o<64;o<<=1){
    float p = __shfl_up(a,o,64);
    if (t>=o) a += p;
  }
  g_acs[(size_t)bh*LSEQ + cix*64 + t] = a;
  if (t==63) g_dAl[(size_t)bh*NC + cix] = a;
}

// ---- depthwise causal conv (k=4) + bias + SiLU, bf16 out ----
__global__ __launch_bounds__(256) void k_conv(const float* __restrict__ cw,
                                              const float* __restrict__ cb) {
  int r0 = blockIdx.x * 4;
  int t0 = r0 & (LSEQ-1);
  int c  = threadIdx.x * 4;
  f32x4 v[7];
  #pragma unroll
  for (int i = 0; i < 7; ++i) {
    int tr = t0 - 3 + i;
    if (tr >= 0)
      v[i] = *(const f32x4*)(&g_zx[(size_t)(r0-3+i)*ZSTR + DIN + c]);
    else
      v[i] = (f32x4){0.f,0.f,0.f,0.f};
  }
  f32x4 w0 = *(const f32x4*)(&cw[(c+0)*4]);
  f32x4 w1 = *(const f32x4*)(&cw[(c+1)*4]);
  f32x4 w2 = *(const f32x4*)(&cw[(c+2)*4]);
  f32x4 w3 = *(const f32x4*)(&cw[(c+3)*4]);
  f32x4 bi = *(const f32x4*)(&cb[c]);
  #pragma unroll
  for (int j = 0; j < 4; ++j) {
    float o[4];
    #pragma unroll
    for (int ch = 0; ch < 4; ++ch) {
      const f32x4& wv = (ch==0)?w0:(ch==1)?w1:(ch==2)?w2:w3;
      float acc = bi[ch];
      #pragma unroll
      for (int k = 0; k < 4; ++k) acc += wv[k] * v[j+k][ch];
      o[ch] = acc / (1.f + __expf(-acc));
    }
    u16 o16[4];
    #pragma unroll
    for (int ch = 0; ch < 4; ++ch) o16[ch] = f2b(o[ch]);
    *(uint2*)(&g_xbcb[(size_t)(r0+j)*CONVD + c]) = *(const uint2*)o16;
  }
}

// ---- Gt = Bm·Cm^T once per (b,c) ----
__global__ __launch_bounds__(256) void k_gmat() {
  int bc = blockIdx.x;
  int b = bc >> 5, cix = bc & 31;
  int row0 = b*LSEQ + cix*64;
  int tid = threadIdx.x, lane = tid & 63, w = tid >> 6;
  int r15 = lane & 15, kq = lane >> 4;
  __shared__ u16 sBm[64*256];
  __shared__ u16 sCm[64*256];
  #pragma unroll
  for (int e = 0; e < 8; ++e) {
    int idx = tid + e*256;
    int row = idx >> 5, c16 = idx & 31;
    uint4 vb = *(const uint4*)(&g_xbcb[(size_t)(row0+row)*CONVD + 512 + c16*8]);
    uint4 vc = *(const uint4*)(&g_xbcb[(size_t)(row0+row)*CONVD + 768 + c16*8]);
    int sw = (c16 ^ (row&7))*8;
    *(uint4*)(&sBm[row*256 + sw]) = vb;
    *(uint4*)(&sCm[row*256 + sw]) = vc;
  }
  __syncthreads();
  int S0 = w*16;
  f32x4 acc[4] = {};
  #pragma unroll
  for (int ks = 0; ks < 8; ++ks) {
    int ch = ks*4 + kq;
    int rA = S0 + r15;
    bf16x8 af = *(const bf16x8*)(&sBm[rA*256 + ((ch ^ (rA&7))*8)]);
    #pragma unroll
    for (int lt = 0; lt < 4; ++lt) {
      int rB = lt*16 + r15;
      bf16x8 bf = *(const bf16x8*)(&sCm[rB*256 + ((ch ^ (rB&7))*8)]);
      acc[lt] = __builtin_amdgcn_mfma_f32_16x16x32_bf16(af, bf, acc[lt], 0, 0, 0);
    }
  }
  float* Gt = &g_gt[(size_t)bc*64*64];
  #pragma unroll
  for (int lt = 0; lt < 4; ++lt)
    #pragma unroll
    for (int j = 0; j < 4; ++j)
      Gt[(S0 + kq*4 + j)*64 + lt*16 + r15] = acc[lt][j];
}

// ---- fused SSD part 1 per (b,c,h) ----
__global__ __launch_bounds__(512) void k_ssd1(const float* __restrict__ Dp) {
  int g = blockIdx.x;
  int h = g & 7, bc = g >> 3;
  int b = bc >> 5, cix = bc & 31;
  int row0 = b*LSEQ + cix*64;
  int bh = b*NHD + h;
  int tid = threadIdx.x;
  int lane = tid & 63, w = tid >> 6;
  int r15 = lane & 15, kq = lane >> 4;

  __shared__ u16 sBmt[256*64];
  __shared__ u16 sXt [64*64];
  __shared__ u16 sXdt[64*64];
  __shared__ u16 sM  [64*64];
  __shared__ float sAc[64];

  {
    int l = tid & 63;
    #pragma unroll
    for (int it = 0; it < 4; ++it) {
      int nc = (tid >> 6) + it*8;
      uint4 v4 = *(const uint4*)(&g_xbcb[(size_t)(row0+l)*CONVD + 512 + nc*8]);
      const u16* hp = (const u16*)&v4;
      #pragma unroll
      for (int i = 0; i < 8; ++i) {
        int n = nc*8 + i;
        sBmt[n*64 + (((l>>3) ^ (n&7))<<3) + (l&7)] = hp[i];
      }
    }
  }
  {
    int s = tid & 63, pc = tid >> 6;
    float ac  = g_acs[(size_t)bh*LSEQ + cix*64 + s];
    float dal = g_dAl[(size_t)bh*NC + cix];
    float dtv = g_dt[(size_t)(row0+s)*NHD + h];
    float dec = __expf(dal - ac);
    if (pc == 0) sAc[s] = ac;
    uint4 v4 = *(const uint4*)(&g_xbcb[(size_t)(row0+s)*CONVD + h*64 + pc*8]);
    const u16* hp = (const u16*)&v4;
    #pragma unroll
    for (int i = 0; i < 8; ++i) {
      int p = pc*8 + i;
      float xv = b2f(hp[i]) * dtv;
      int sw = (((s>>3) ^ (p&7))<<3) + (s&7);
      sXt [p*64 + sw] = f2b(xv);
      sXdt[p*64 + sw] = f2b(xv*dec);
    }
  }
  __syncthreads();

  {
    int S0  = (w >> 1)*16;
    int L0a = ((2*w) & 3)*16, L0b = L0a + 16;
    const float* Gt = &g_gt[(size_t)bc*64*64];
    int l0 = L0a + r15, l1 = L0b + r15;
    float acl0 = sAc[l0], acl1 = sAc[l1];
    #pragma unroll
    for (int j = 0; j < 4; ++j) {
      int s_ = S0 + kq*4 + j;
      float acs_ = sAc[s_];
      float g0 = Gt[s_*64 + l0];
      float g1 = Gt[s_*64 + l1];
      float m0 = (s_ <= l0) ? g0*__expf(acl0 - acs_) : 0.f;
      float m1 = (s_ <= l1) ? g1*__expf(acl1 - acs_) : 0.f;
      sM[l0*64 + (((s_>>3) ^ (l0&7))<<3) + (s_&7)] = f2b(m0);
      sM[l1*64 + (((s_>>3) ^ (l1&7))<<3) + (s_&7)] = f2b(m1);
    }
  }
  __syncthreads();

  {
    int lt = w >> 1;
    int pt0 = (2*w) & 3;
    int L0 = lt*16, P0 = pt0*16;
    f32x4 acc0 = {}, acc1 = {};
    #pragma unroll
    for (int ks = 0; ks < 2; ++ks) {
      int ch = ks*4 + kq;
      int sw = (ch ^ (r15&7))<<3;
      bf16x8 af = *(const bf16x8*)(&sM [(L0+r15)*64 + sw]);
      bf16x8 b0 = *(const bf16x8*)(&sXt[(P0+r15)*64 + sw]);
      bf16x8 b1 = *(const bf16x8*)(&sXt[(P0+16+r15)*64 + sw]);
      acc0 = __builtin_amdgcn_mfma_f32_16x16x32_bf16(af, b0, acc0, 0, 0, 0);
      acc1 = __builtin_amdgcn_mfma_f32_16x16x32_bf16(af, b1, acc1, 0, 0, 0);
    }
    float Dv = Dp[h];
    #pragma unroll
    for (int j = 0; j < 4; ++j) {
      int l = L0 + kq*4 + j;
      int p0 = P0 + r15, p1 = p0 + 16;
      float xh0 = b2f(g_xbcb[(size_t)(row0+l)*CONVD + h*64 + p0]);
      float xh1 = b2f(g_xbcb[(size_t)(row0+l)*CONVD + h*64 + p1]);
      g_y[(size_t)(row0+l)*DIN + h*64 + p0] = acc0[j] + Dv*xh0;
      g_y[(size_t)(row0+l)*DIN + h*64 + p1] = acc1[j] + Dv*xh1;
    }
  }

  {
    int P0 = (w >> 1)*16;
    int N0 = (w & 1)*128;
    f32x4 acc[8] = {};
    #pragma unroll
    for (int ks = 0; ks < 2; ++ks) {
      int ch = ks*4 + kq;
      int sw = (ch ^ (r15&7))<<3;
      bf16x8 af = *(const bf16x8*)(&sXdt[(P0+r15)*64 + sw]);
      #pragma unroll
      for (int nt = 0; nt < 8; ++nt) {
        bf16x8 bf = *(const bf16x8*)(&sBmt[(N0+nt*16+r15)*64 + sw]);
        acc[nt] = __builtin_amdgcn_mfma_f32_16x16x32_bf16(af, bf, acc[nt], 0, 0, 0);
      }
    }
    size_t Sbase = ((size_t)(bc*NHD + h))*PD*DSTATE;
    #pragma unroll
    for (int nt = 0; nt < 8; ++nt)
      #pragma unroll
      for (int j = 0; j < 4; ++j) {
        int p = P0 + kq*4 + j;
        int n = N0 + nt*16 + r15;
        g_Sb[Sbase + (size_t)p*DSTATE + n] = f2b(acc[nt][j]);
      }
  }
}

// ---- exclusive inter-chunk scan (bf16 storage, fp32 carry) ----
__global__ void k_sscan() {
  int i = blockIdx.x*256 + threadIdx.x;
  int pn = i & (PD*DSTATE-1);
  int bh = i >> 14;
  int b = bh >> 3, h = bh & 7;
  float carry = 0.f;
  for (int c=0;c<NC;c++){
    size_t off = ((size_t)((b*NC+c)*NHD + h))*PD*DSTATE + pn;
    float cur = b2f(g_Sb[off]);
    g_Sb[off] = f2b(carry);
    carry = carry*__expf(g_dAl[(size_t)(b*NHD+h)*NC + c]) + cur;
  }
}

// ---- fused SSD part 2 per (b,c,h) ----
__global__ __launch_bounds__(256) void k_ssd2() {
  int g = blockIdx.x;
  int h = g & 7, bc = g >> 3;
  int b = bc >> 5, cix = bc & 31;
  int row0 = b*LSEQ + cix*64;
  int bh = b*NHD + h;
  int tid = threadIdx.x;
  int lane = tid & 63, w = tid >> 6;
  int r15 = lane & 15, kq = lane >> 4;
  __shared__ u16 sSb[64*256];
  __shared__ float sAc[64];
  size_t Sbase = ((size_t)(bc*NHD + h))*PD*DSTATE;
  #pragma unroll
  for (int it = 0; it < 8; ++it) {
    int e = tid + it*256;
    int c16 = e & 31, p = e >> 5;
    uint4 v4 = *(const uint4*)(&g_Sb[Sbase + (size_t)p*DSTATE + c16*8]);
    *(uint4*)(&sSb[p*256 + ((c16 ^ (p&7))<<3)]) = v4;
  }
  if (tid < 64) sAc[tid] = g_acs[(size_t)bh*LSEQ + cix*64 + tid];
  __syncthreads();
  int L0 = w*16;
  const u16* Ab = &g_xbcb[(size_t)(row0+L0+r15)*CONVD + 768];
  f32x4 acc[4] = {};
  #pragma unroll
  for (int ks = 0; ks < 8; ++ks) {
    int ch = ks*4 + kq;
    bf16x8 af = *(const bf16x8*)(Ab + ch*8);
    #pragma unroll
    for (int pt = 0; pt < 4; ++pt) {
      bf16x8 bf = *(const bf16x8*)(&sSb[(pt*16+r15)*256 + ((ch ^ (r15&7))<<3)]);
      acc[pt] = __builtin_amdgcn_mfma_f32_16x16x32_bf16(af, bf, acc[pt], 0, 0, 0);
    }
  }
  #pragma unroll
  for (int j = 0; j < 4; ++j) {
    int l = L0 + kq*4 + j;
    float ev = __expf(sAc[l]);
    #pragma unroll
    for (int pt = 0; pt < 4; ++pt) {
      int p = pt*16 + r15;
      g_y[(size_t)(row0+l)*DIN + h*64 + p] += ev*acc[pt][j];
    }
  }
}

// ---- gated RMSNorm over 512, vectorized: 2 rows/block, f32x4/thread ----
__global__ void k_gated(const float* __restrict__ gw) {
  int rl = threadIdx.x >> 7;
  int row = blockIdx.x*2 + rl;
  int t = threadIdx.x & 127;
  f32x4 y4 = *(const f32x4*)(&g_y[(size_t)row*DIN + t*4]);
  f32x4 z4 = *(const f32x4*)(&g_zx[(size_t)row*ZSTR + t*4]);
  float v[4]; float ss = 0.f;
  #pragma unroll
  for (int j = 0; j < 4; ++j) {
    float z = z4[j];
    float val = y4[j] * (z/(1.f+__expf(-z)));
    v[j] = val; ss += val*val;
  }
  #pragma unroll
  for (int o=32;o>0;o>>=1) ss += __shfl_down(ss,o,64);
  __shared__ float ls[4];
  if ((threadIdx.x&63)==0) ls[threadIdx.x>>6]=ss;
  __syncthreads();
  float tot = ls[rl*2] + ls[rl*2+1];
  float r = rsqrtf(tot*(1.f/DIN) + EPS);
  u16 o16[4];
  #pragma unroll
  for (int j = 0; j < 4; ++j) o16[j] = f2b(v[j]*r*gw[t*4+j]);
  *(uint2*)(&g_yb[(size_t)row*DIN + t*4]) = *(const uint2*)o16;
}

extern "C" void kernel_launch(void* const* d_in, const int* in_sizes, int n_in,
                              void* d_out, int out_size, void* d_ws, size_t ws_size,
                              hipStream_t stream) {
  const float* x     = (const float*)d_in[0];
  const float* emb   = (const float*)d_in[1];
  const float* inpw  = (const float*)d_in[2];
  const float* convw = (const float*)d_in[3];
  const float* convb = (const float*)d_in[4];
  const float* dtb   = (const float*)d_in[5];
  const float* alog  = (const float*)d_in[6];
  const float* Dp    = (const float*)d_in[7];
  const float* gnw   = (const float*)d_in[8];
  const float* outw  = (const float*)d_in[9];
  const float* normw = (const float*)d_in[10];
  const float* normf = (const float*)d_in[11];
  const float* headw = (const float*)d_in[12];
  float* out = (float*)d_out;
  (void)in_sizes; (void)n_in; (void)out_size; (void)d_ws; (void)ws_size;

  float *ph, *pzx;
  u16 *pub, *pyb, *pwt1, *pwt2, *pwt3;
  hipGetSymbolAddress((void**)&ph,   HIP_SYMBOL(g_h));
  hipGetSymbolAddress((void**)&pub,  HIP_SYMBOL(g_ub));
  hipGetSymbolAddress((void**)&pzx,  HIP_SYMBOL(g_zx));
  hipGetSymbolAddress((void**)&pyb,  HIP_SYMBOL(g_yb));
  hipGetSymbolAddress((void**)&pwt1, HIP_SYMBOL(g_wt1));
  hipGetSymbolAddress((void**)&pwt2, HIP_SYMBOL(g_wt2));
  hipGetSymbolAddress((void**)&pwt3, HIP_SYMBOL(g_wt3));

  k_embedrms<<<BL, 256, 0, stream>>>(x, emb, normw);
  k_wtall<<<280, 256, 0, stream>>>(inpw, outw, headw);
  for (int i=0;i<NLAY;i++){
    k_mfma_gemm<EMBD,false><<<dim3(ZSTR/64, BL/128), 256, 0, stream>>>(
        pub, pwt1 + (size_t)i*ZSTR*EMBD, nullptr, pzx, ZSTR);
    k_dtscan<<<NB*NHD*NC, 64, 0, stream>>>(dtb + i*NHD, alog + i*NHD);
    k_conv<<<BL/4, 256, 0, stream>>>(convw + i*CONVD*4, convb + i*CONVD);
    k_gmat<<<NB*NC, 256, 0, stream>>>();
    k_ssd1<<<NB*NC*NHD, 512, 0, stream>>>(Dp + i*NHD);
    k_sscan<<<(NB*NHD*PD*DSTATE)/256, 256, 0, stream>>>();
    k_ssd2<<<NB*NC*NHD, 256, 0, stream>>>();
    k_gated<<<BL/2, 256, 0, stream>>>(gnw + i*DIN);
    k_mfma_gemm<DIN,true><<<dim3(EMBD/64, BL/128), 256, 0, stream>>>(
        pyb, pwt2 + (size_t)i*EMBD*DIN, ph, ph, EMBD);
    k_rmsnorm<<<BL, 256, 0, stream>>>(ph, (i==NLAY-1) ? normf : normw + (i+1)*EMBD, pub);
  }
  k_mfma_gemm<EMBD,false><<<dim3(EMBD/64, BL/128), 256, 0, stream>>>(pub, pwt3, nullptr, out, EMBD);
}